// Round 13
// baseline (75.840 us; speedup 1.0000x reference)
//
#include <hip/hip_runtime.h>

#define N_BONDS 50000
#define N_EDGES 600000
#define R_BONDS 4
#define THREADS 512
#define BONDS_PER_BLOCK 32     // 8 waves * 4 bonds
#define STARTS_BLOCKS ((N_EDGES + 255) / 256)          // 2344
#define PREMUL_BLOCKS ((N_BONDS + 31) / 32)            // 1563

typedef float f4 __attribute__((ext_vector_type(4)));
typedef unsigned short u16x4 __attribute__((ext_vector_type(4)));

__device__ __forceinline__ float bcastf(float v, int l) {
    return __builtin_bit_cast(float, __builtin_amdgcn_readlane(__builtin_bit_cast(int, v), l));
}
__device__ __forceinline__ f4 f4zero() { return (f4){0.f, 0.f, 0.f, 0.f}; }
__device__ __forceinline__ void fma4(f4& a, float s, const f4& b) {
    a.x = fmaf(s, b.x, a.x); a.y = fmaf(s, b.y, a.y);
    a.z = fmaf(s, b.z, a.z); a.w = fmaf(s, b.w, a.w);
}
__device__ __forceinline__ float bf2f(unsigned short u) {
    return __builtin_bit_cast(float, ((unsigned)u) << 16);
}
__device__ __forceinline__ unsigned short f2bf(float f) {   // RNE
    unsigned u = __builtin_bit_cast(unsigned, f);
    return (unsigned short)((u + 0x7fffu + ((u >> 16) & 1u)) >> 16);
}
__device__ __forceinline__ f4 cvt4(u16x4 u) {
    return (f4){bf2f(u.x), bf2f(u.y), bf2f(u.z), bf2f(u.w)};
}

// ---- K0: starts[] (blocks 0..2343) + bondKb = bf16(bond @ Ktop) (blocks 2344..) ----
__global__ __launch_bounds__(256)
void prep(const int* __restrict__ edges, int* __restrict__ starts,
          const float* __restrict__ bond, const float* __restrict__ Kmat,
          unsigned short* __restrict__ bondKb) {
    __shared__ float ldsK[64 * 64];   // 16 KB (premul branch only)
    const int tid = threadIdx.x;

    if (blockIdx.x < STARTS_BLOCKS) {
        const int e = blockIdx.x * 256 + tid;
        if (e >= N_EDGES) return;
        const int2* edges2 = (const int2*)edges;
        const int s  = edges2[e].x;
        const int sp = (e == 0) ? -1 : edges2[e - 1].x;
        for (int b = sp + 1; b <= s; ++b) starts[b] = e;
        if (e == N_EDGES - 1)
            for (int b = s + 1; b <= N_BONDS; ++b) starts[b] = N_EDGES;
        return;
    }

    // ---- premul: 32 rows per block, 8 per wave ----
    const int bid  = blockIdx.x - STARTS_BLOCKS;
    const int lane = tid & 63;
    const int wid  = tid >> 6;
    {
        const f4* K4 = (const f4*)Kmat;            // Ktop = first 1024 f4
        f4* L4 = (f4*)ldsK;
        #pragma unroll
        for (int i = 0; i < 4; ++i) L4[tid + i * 256] = K4[tid + i * 256];
    }
    __syncthreads();
    const int row0 = bid * 32 + wid * 8;
    if (row0 >= N_BONDS) return;

    float rowv[8], acc[8];
    #pragma unroll
    for (int r = 0; r < 8; ++r) {
        int ri = row0 + r; if (ri >= N_BONDS) ri = N_BONDS - 1;
        rowv[r] = bond[ri * 64 + lane];
        acc[r]  = 0.f;
    }
    #pragma unroll 4
    for (int d = 0; d < 64; ++d) {
        const float k = ldsK[d * 64 + lane];       // lane = output unit
        #pragma unroll
        for (int r = 0; r < 8; ++r)
            acc[r] = fmaf(bcastf(rowv[r], d), k, acc[r]);
    }
    #pragma unroll
    for (int r = 0; r < 8; ++r)
        if (row0 + r < N_BONDS)
            bondKb[(row0 + r) * 64 + lane] = f2bf(acc[r]);   // 128B/row, contiguous
}

// ---- K1: fused gather(bondKb) + segsum + Kbot-matvec ----
__global__ __launch_bounds__(THREADS, 4)
void fused_gather_segsum_mm(const unsigned short* __restrict__ bondKb, // [N_BONDS][64] bf16
                            const float* __restrict__ sph,    // [N_EDGES][64]
                            const int*   __restrict__ edges,  // [N_EDGES][2]
                            const float* __restrict__ Kmat,   // [128][64]
                            const float* __restrict__ bias,   // [64]
                            const int*   __restrict__ starts, // [N_BONDS+1]
                            float* __restrict__ out)          // [N_BONDS][64]
{
    __shared__ float ldsK[64 * 64];   // 16 KB: Kbot only
    const int tid  = threadIdx.x;
    const int lane = tid & 63;
    const int wid  = tid >> 6;
    const int fl   = lane & 15;   // f4-column within a 64-float row
    const int sg   = lane >> 4;   // subgroup = edge-within-quad

    {   // stage Kbot (rows 64..127 = f4 index 1024..2047)
        const f4* K4 = (const f4*)Kmat;
        f4*       L4 = (f4*)ldsK;
        #pragma unroll
        for (int i = 0; i < 2; ++i) L4[tid + i * THREADS] = K4[1024 + tid + i * THREADS];
    }
    __syncthreads();                                   // only barrier

    const int b0 = blockIdx.x * BONDS_PER_BLOCK + wid * R_BONDS;
    if (b0 >= N_BONDS) return;

    int st[R_BONDS + 1];                               // SGPR, static-indexed only
    #pragma unroll
    for (int r = 0; r <= R_BONDS; ++r)
        st[r] = __builtin_amdgcn_readfirstlane(starts[b0 + r]);

    const int eb    = st[0];
    const int total = st[R_BONDS] - eb;

    const u16x4* bk4    = (const u16x4*)bondKb;
    const f4*    sph4   = (const f4*)sph;
    const int2*  edges2 = (const int2*)edges;

    float slotG[R_BONDS], slotS[R_BONDS];              // static-indexed only
    f4 aG = f4zero(), aS = f4zero();
    int r = 0, cs = 0, bnd = st[1] - eb;

    // cross-subgroup reduce + transpose f4 layout -> scalar layout (lane d = feat d)
    auto txr = [&](f4 v) -> float {
        v.x += __shfl_xor(v.x, 16); v.y += __shfl_xor(v.y, 16);
        v.z += __shfl_xor(v.z, 16); v.w += __shfl_xor(v.w, 16);
        v.x += __shfl_xor(v.x, 32); v.y += __shfl_xor(v.y, 32);
        v.z += __shfl_xor(v.z, 32); v.w += __shfl_xor(v.w, 32);
        const int src = lane >> 2;
        const float s0 = __shfl(v.x, src), s1 = __shfl(v.y, src);
        const float s2 = __shfl(v.z, src), s3 = __shfl(v.w, src);
        const float r01 = (lane & 1) ? s1 : s0;
        const float r23 = (lane & 1) ? s3 : s2;
        return (lane & 2) ? r23 : r01;
    };

    // boundary path: masked add, close bonds that end inside this quad
    auto slowpath = [&](int q, f4 GV, f4 SV) {
        const int qe = q + sg;
        while (true) {
            const float m = (qe >= cs && qe < bnd) ? 1.f : 0.f;
            fma4(aG, m, GV); fma4(aS, m, SV);
            if (bnd > q + 4) break;                    // bond continues past quad
            const float tG = txr(aG), tS = txr(aS);    // close bond r
            #pragma unroll
            for (int rr = 0; rr < R_BONDS; ++rr)
                if (rr == r) { slotG[rr] = tG; slotS[rr] = tS; }
            aG = f4zero(); aS = f4zero();
            cs = bnd;
            ++r;
            if (r >= R_BONDS) { bnd = 0x7fffffff; break; }
            #pragma unroll
            for (int rr = 2; rr <= R_BONDS; ++rr)
                if (r + 1 == rr) bnd = st[rr] - eb;
        }
    };

    int w0 = 0;
    while (w0 < total) {
        int wlen = total - w0; if (wlen > 64) wlen = 64;
        int2 p = make_int2(0, 0);
        if (lane < wlen) p = edges2[eb + w0 + lane];   // one coalesced index window
        const int ng = (wlen + 3) >> 2;

        u16x4 uA, uB, uC, uD;
        f4 sA, sB, sC, sD;

#define ISS(QQ, UV, SV) do { \
        if ((QQ) < ng) { \
            const int idx_ = (QQ) * 4 + sg; \
            const int nbr_ = __shfl(p.y, idx_); \
            int qe_ = w0 + idx_; if (qe_ >= total) qe_ = total - 1; \
            UV = bk4[nbr_ * 16 + fl]; \
            SV = sph4[(eb + qe_) * 16 + fl]; \
        } else { UV = (u16x4){0,0,0,0}; SV = f4zero(); } } while (0)

#define ACC(QQ, UV, SV) do { \
        const int q_ = w0 + (QQ) * 4; \
        const f4 GVf = cvt4(UV); \
        if (q_ + 4 <= bnd) { aG += GVf; aS += SV; } \
        else slowpath(q_, GVf, SV); } while (0)

        ISS(0, uA, sA); ISS(1, uB, sB); ISS(2, uC, sC); ISS(3, uD, sD);
        int q = 0;
        for (; q + 4 <= ng; q += 4) {                  // rotated: 8 loads in flight
            ACC(q + 0, uA, sA); ISS(q + 4, uA, sA);
            ACC(q + 1, uB, sB); ISS(q + 5, uB, sB);
            ACC(q + 2, uC, sC); ISS(q + 6, uC, sC);
            ACC(q + 3, uD, sD); ISS(q + 7, uD, sD);
        }
        if (q + 0 < ng) ACC(q + 0, uA, sA);            // tail (<=3 quads)
        if (q + 1 < ng) ACC(q + 1, uB, sB);
        if (q + 2 < ng) ACC(q + 2, uC, sC);
#undef ISS
#undef ACC
        w0 += wlen;
    }

    {   // close remaining open/empty bonds
        const float tG = txr(aG), tS = txr(aS);
        #pragma unroll
        for (int rr = 0; rr < R_BONDS; ++rr) {
            if (rr == r)     { slotG[rr] = tG;  slotS[rr] = tS; }
            else if (rr > r) { slotG[rr] = 0.f; slotS[rr] = 0.f; }
        }
    }

    // ---- deferred matvec: S-half only (G-half is already in output space) ----
    float acc[R_BONDS];
    const float bl = bias[lane];
    #pragma unroll
    for (int rr = 0; rr < R_BONDS; ++rr) acc[rr] = slotG[rr] + bl;

    #pragma unroll 4
    for (int d = 0; d < 64; ++d) {
        const float kb = ldsK[d * 64 + lane];          // 2-way bank alias: free
        #pragma unroll
        for (int rr = 0; rr < R_BONDS; ++rr)
            acc[rr] = fmaf(bcastf(slotS[rr], d), kb, acc[rr]);
    }

    #pragma unroll
    for (int rr = 0; rr < R_BONDS; ++rr)
        if (b0 + rr < N_BONDS)
            __builtin_nontemporal_store(acc[rr], &out[(b0 + rr) * 64 + lane]);
}

extern "C" void kernel_launch(void* const* d_in, const int* in_sizes, int n_in,
                              void* d_out, int out_size, void* d_ws, size_t ws_size,
                              hipStream_t stream) {
    const float* bond  = (const float*)d_in[0];
    const float* sph   = (const float*)d_in[1];
    const int*   edges = (const int*)d_in[2];
    const float* Kmat  = (const float*)d_in[3];
    const float* bias  = (const float*)d_in[4];
    float* out = (float*)d_out;

    int*            starts = (int*)d_ws;                          // 200 KB
    unsigned short* bondKb = (unsigned short*)((char*)d_ws + 262144);  // 6.4 MB

    prep<<<STARTS_BLOCKS + PREMUL_BLOCKS, 256, 0, stream>>>(edges, starts,
                                                            bond, Kmat, bondKb);

    const int nblocks = (N_BONDS + BONDS_PER_BLOCK - 1) / BONDS_PER_BLOCK;
    fused_gather_segsum_mm<<<nblocks, THREADS, 0, stream>>>(bondKb, sph, edges, Kmat,
                                                            bias, starts, out);
}

// Round 14
// 72.939 us; speedup vs baseline: 1.0398x; 1.0398x over previous
//
#include <hip/hip_runtime.h>

#define N_BONDS 50000
#define N_EDGES 600000
#define R_BONDS 4
#define THREADS 512
#define BONDS_PER_BLOCK 32   // 8 waves * 4 bonds

typedef float f4 __attribute__((ext_vector_type(4)));

__device__ __forceinline__ float bcastf(float v, int l) {
    return __builtin_bit_cast(float, __builtin_amdgcn_readlane(__builtin_bit_cast(int, v), l));
}
__device__ __forceinline__ f4 f4zero() { return (f4){0.f, 0.f, 0.f, 0.f}; }
__device__ __forceinline__ void fma4(f4& a, float s, const f4& b) {
    a.x = fmaf(s, b.x, a.x); a.y = fmaf(s, b.y, a.y);
    a.z = fmaf(s, b.z, a.z); a.w = fmaf(s, b.w, a.w);
}

// ---- kernel 1: starts[b] = lower_bound(seg, b), b in [0, N_BONDS] ----
__global__ __launch_bounds__(256)
void fill_starts(const int* __restrict__ edges, int* __restrict__ starts) {
    const int e = blockIdx.x * blockDim.x + threadIdx.x;
    if (e >= N_EDGES) return;
    const int2* edges2 = (const int2*)edges;
    const int s  = edges2[e].x;
    const int sp = (e == 0) ? -1 : edges2[e - 1].x;
    for (int b = sp + 1; b <= s; ++b) starts[b] = e;
    if (e == N_EDGES - 1)
        for (int b = s + 1; b <= N_BONDS; ++b) starts[b] = N_EDGES;
}

// ---- kernel 2: fused gather + segsum + matvec, 3-stage pipeline ----
__global__ __launch_bounds__(THREADS, 4)   // VGPR cap 128
void fused_gather_segsum_mm(const float* __restrict__ bond,   // [N_BONDS][64]
                            const float* __restrict__ sph,    // [N_EDGES][64]
                            const int*   __restrict__ edges,  // [N_EDGES][2]
                            const float* __restrict__ Kmat,   // [128][64]
                            const float* __restrict__ bias,   // [64]
                            const int*   __restrict__ starts, // [N_BONDS+1]
                            float* __restrict__ out)          // [N_BONDS][64]
{
    __shared__ float ldsK[128 * 64];   // 32 KB shared by 8 waves
    const int tid  = threadIdx.x;
    const int lane = tid & 63;
    const int wid  = tid >> 6;
    const int fl   = lane & 15;   // f4-column within a 64-float row
    const int sg   = lane >> 4;   // subgroup = edge-within-quad

    {   // stage K, coalesced 16B
        const f4* K4 = (const f4*)Kmat;
        f4*       L4 = (f4*)ldsK;
        #pragma unroll
        for (int i = 0; i < 4; ++i) L4[tid + i * THREADS] = K4[tid + i * THREADS];
    }
    __syncthreads();                                   // only barrier

    const int b0 = blockIdx.x * BONDS_PER_BLOCK + wid * R_BONDS;
    if (b0 >= N_BONDS) return;

    int st[R_BONDS + 1];                               // SGPR, static-indexed only
    #pragma unroll
    for (int r = 0; r <= R_BONDS; ++r)
        st[r] = __builtin_amdgcn_readfirstlane(starts[b0 + r]);

    const int eb    = st[0];
    const int total = st[R_BONDS] - eb;
    const int nq    = (total + 3) >> 2;                // quads

    const f4* bond4 = (const f4*)bond;
    const f4* sph4  = (const f4*)sph;

    float slotG[R_BONDS], slotS[R_BONDS];              // static-indexed only
    f4 aG = f4zero(), aS = f4zero();
    int r = 0, cs = 0, bnd = st[1] - eb;

    // cross-subgroup reduce + transpose f4 layout -> scalar layout (lane d = feat d)
    auto txr = [&](f4 v) -> float {
        v.x += __shfl_xor(v.x, 16); v.y += __shfl_xor(v.y, 16);
        v.z += __shfl_xor(v.z, 16); v.w += __shfl_xor(v.w, 16);
        v.x += __shfl_xor(v.x, 32); v.y += __shfl_xor(v.y, 32);
        v.z += __shfl_xor(v.z, 32); v.w += __shfl_xor(v.w, 32);
        const int src = lane >> 2;
        const float s0 = __shfl(v.x, src), s1 = __shfl(v.y, src);
        const float s2 = __shfl(v.z, src), s3 = __shfl(v.w, src);
        const float r01 = (lane & 1) ? s1 : s0;
        const float r23 = (lane & 1) ? s3 : s2;
        return (lane & 2) ? r23 : r01;
    };

    // boundary path: masked add, close bonds that end inside this quad
    auto slowpath = [&](int q, f4 GV, f4 SV) {
        const int qe = q + sg;
        while (true) {
            const float m = (qe >= cs && qe < bnd) ? 1.f : 0.f;
            fma4(aG, m, GV); fma4(aS, m, SV);
            if (bnd > q + 4) break;                    // bond continues past quad
            const float tG = txr(aG), tS = txr(aS);    // close bond r
            #pragma unroll
            for (int rr = 0; rr < R_BONDS; ++rr)
                if (rr == r) { slotG[rr] = tG; slotS[rr] = tS; }
            aG = f4zero(); aS = f4zero();
            cs = bnd;
            ++r;
            if (r >= R_BONDS) { bnd = 0x7fffffff; break; }
            #pragma unroll
            for (int rr = 2; rr <= R_BONDS; ++rr)
                if (r + 1 == rr) bnd = st[rr] - eb;
        }
    };

    // stage 1: subgroup-uniform index load (prefetched 8 quads ahead; off the chain)
    auto loadIdx = [&](int Q) -> int {
        if (Q >= nq) return 0;                         // uniform guard: no load
        int e = 4 * Q + sg;
        e = (e < total) ? e : total - 1;
        return edges[2 * (eb + e) + 1];                // 4 dwords/wave, 16x replicated
    };
    // stage 2: data loads from a ready index register
    auto issData = [&](int nbr, int Q, f4& GV, f4& SV) {
        int e = 4 * Q + sg;
        e = (e < total) ? e : total - 1;
        GV = bond4[nbr * 16 + fl];
        SV = sph4[(eb + e) * 16 + fl];
    };
    // stage 3: accumulate (wave-uniform segment logic)
    auto accq = [&](int Q, f4 GV, f4 SV) {
        const int q_ = Q * 4;
        if (q_ + 4 <= bnd) { aG += GV; aS += SV; }
        else slowpath(q_, GV, SV);
    };

    if (nq > 0) {
        f4 gA = f4zero(), sA = f4zero(), gB = f4zero(), sB = f4zero();
        f4 gC = f4zero(), sC = f4zero(), gD = f4zero(), sD = f4zero();

        int i0 = loadIdx(0), i1 = loadIdx(1), i2 = loadIdx(2), i3 = loadIdx(3);
        int j0 = loadIdx(4), j1 = loadIdx(5), j2 = loadIdx(6), j3 = loadIdx(7);

        issData(i0, 0, gA, sA);
        if (1 < nq) issData(i1, 1, gB, sB);
        if (2 < nq) issData(i2, 2, gC, sC);
        if (3 < nq) issData(i3, 3, gD, sD);
        i0 = j0; i1 = j1; i2 = j2; i3 = j3;
        j0 = loadIdx(8); j1 = loadIdx(9); j2 = loadIdx(10); j3 = loadIdx(11);

        for (int q = 0; q < nq; q += 4) {
            accq(q + 0, gA, sA);
            if (q + 4 < nq) issData(i0, q + 4, gA, sA);
            if (q + 1 < nq) { accq(q + 1, gB, sB); if (q + 5 < nq) issData(i1, q + 5, gB, sB); }
            if (q + 2 < nq) { accq(q + 2, gC, sC); if (q + 6 < nq) issData(i2, q + 6, gC, sC); }
            if (q + 3 < nq) { accq(q + 3, gD, sD); if (q + 7 < nq) issData(i3, q + 7, gD, sD); }
            i0 = j0; i1 = j1; i2 = j2; i3 = j3;
            j0 = loadIdx(q + 12); j1 = loadIdx(q + 13);
            j2 = loadIdx(q + 14); j3 = loadIdx(q + 15);
        }
    }

    {   // close remaining open/empty bonds
        const float tG = txr(aG), tS = txr(aS);
        #pragma unroll
        for (int rr = 0; rr < R_BONDS; ++rr) {
            if (rr == r)     { slotG[rr] = tG;  slotS[rr] = tS; }
            else if (rr > r) { slotG[rr] = 0.f; slotS[rr] = 0.f; }
        }
    }

    // ---- deferred matvec: 4 bonds amortize each LDS K read ----
    float acc[R_BONDS];
    const float bl = bias[lane];
    #pragma unroll
    for (int rr = 0; rr < R_BONDS; ++rr) acc[rr] = bl;

    #pragma unroll 4
    for (int d = 0; d < 64; ++d) {
        const float kt = ldsK[d * 64 + lane];          // 2-way bank alias: free
        const float kb = ldsK[(64 + d) * 64 + lane];
        #pragma unroll
        for (int rr = 0; rr < R_BONDS; ++rr) {
            acc[rr] = fmaf(bcastf(slotG[rr], d), kt, acc[rr]);
            acc[rr] = fmaf(bcastf(slotS[rr], d), kb, acc[rr]);
        }
    }

    #pragma unroll
    for (int rr = 0; rr < R_BONDS; ++rr)
        if (b0 + rr < N_BONDS)
            __builtin_nontemporal_store(acc[rr], &out[(b0 + rr) * 64 + lane]);
}

extern "C" void kernel_launch(void* const* d_in, const int* in_sizes, int n_in,
                              void* d_out, int out_size, void* d_ws, size_t ws_size,
                              hipStream_t stream) {
    const float* bond  = (const float*)d_in[0];
    const float* sph   = (const float*)d_in[1];
    const int*   edges = (const int*)d_in[2];
    const float* Kmat  = (const float*)d_in[3];
    const float* bias  = (const float*)d_in[4];
    float* out  = (float*)d_out;
    int* starts = (int*)d_ws;                          // (N_BONDS+1)*4 = 200 KB

    fill_starts<<<(N_EDGES + 255) / 256, 256, 0, stream>>>(edges, starts);

    const int nblocks = (N_BONDS + BONDS_PER_BLOCK - 1) / BONDS_PER_BLOCK;
    fused_gather_segsum_mm<<<nblocks, THREADS, 0, stream>>>(bond, sph, edges, Kmat,
                                                            bias, starts, out);
}